// Round 5
// baseline (410.570 us; speedup 1.0000x reference)
//
#include <hip/hip_runtime.h>
#include <hip/hip_bf16.h>
#include <cfloat>

// dims
#define N_B 32
#define QN 64
#define FN 16
#define LP 196
#define HN 12
#define DH 64
#define EE 768
#define KLEN 3136
#define FPB 4          // frames per block (attn)
#define KROWS 208      // padded patches per frame for QK (13*16)
#define VST 256        // Vt_s row stride in bf16 (512B, pow2 for XOR swizzle)
#define PST 232        // Pt_s row stride in bf16 (464B = 29*16B, conflict-audited free)

typedef short s16x4 __attribute__((ext_vector_type(4)));
typedef __bf16 bf16x8 __attribute__((ext_vector_type(8)));
typedef float f32x4 __attribute__((ext_vector_type(4)));

__device__ __forceinline__ bf16x8 cvt8(f32x4 a, f32x4 b) {
    bf16x8 r;
    r[0] = (__bf16)a[0]; r[1] = (__bf16)a[1]; r[2] = (__bf16)a[2]; r[3] = (__bf16)a[3];
    r[4] = (__bf16)b[0]; r[5] = (__bf16)b[1]; r[6] = (__bf16)b[2]; r[7] = (__bf16)b[3];
    return r;
}
__device__ __forceinline__ unsigned short bfb(float x) {
    return __builtin_bit_cast(unsigned short, (__bf16)x);
}

// ---------------------------------------------------------------------------
// bf16 MFMA GEMM: C[m][n] = sum_k A[m][k] * W[n][k]  (fp32 in, fp32 out)
// BM=64, BN=48, BK=32; 256 threads = 4 waves; wave w owns rows w*16..+16.
// ---------------------------------------------------------------------------
__global__ __launch_bounds__(256) void gemm_mfma(const float* __restrict__ A,
                                                 const float* __restrict__ W,
                                                 float* __restrict__ C) {
    __shared__ unsigned short As[64 * 72];
    __shared__ unsigned short Ws[48 * 72];
    const int t = threadIdx.x;
    const int w = t >> 6, lane = t & 63, lr = lane & 15, lg = lane >> 4;
    const int m0 = blockIdx.x * 64;
    const int n0 = blockIdx.y * 48;

    f32x4 acc[3];
#pragma unroll
    for (int ct = 0; ct < 3; ++ct) acc[ct] = (f32x4){0.f, 0.f, 0.f, 0.f};

    for (int k0 = 0; k0 < EE; k0 += 32) {
        {
            int row = t >> 2, cb = t & 3;
            const float* src = A + (size_t)(m0 + row) * EE + k0 + cb * 8;
            f32x4 a = *(const f32x4*)src, b = *(const f32x4*)(src + 4);
            *(bf16x8*)&As[row * 72 + cb * 8] = cvt8(a, b);
        }
        if (t < 192) {
            int row = t >> 2, cb = t & 3;
            const float* src = W + (size_t)(n0 + row) * EE + k0 + cb * 8;
            f32x4 a = *(const f32x4*)src, b = *(const f32x4*)(src + 4);
            *(bf16x8*)&Ws[row * 72 + cb * 8] = cvt8(a, b);
        }
        __syncthreads();
        bf16x8 a = *(const bf16x8*)&As[(w * 16 + lr) * 72 + lg * 8];
#pragma unroll
        for (int ct = 0; ct < 3; ++ct) {
            bf16x8 b = *(const bf16x8*)&Ws[(ct * 16 + lr) * 72 + lg * 8];
            acc[ct] = __builtin_amdgcn_mfma_f32_16x16x32_bf16(a, b, acc[ct], 0, 0, 0);
        }
        __syncthreads();
    }
#pragma unroll
    for (int ct = 0; ct < 3; ++ct)
#pragma unroll
        for (int r = 0; r < 4; ++r)
            C[(size_t)(m0 + w * 16 + lg * 4 + r) * EE + n0 + ct * 16 + lr] = acc[ct][r];
}

__global__ __launch_bounds__(256) void zero_f32(float* __restrict__ p, int n4) {
    int i = blockIdx.x * 256 + threadIdx.x;
    if (i < n4) ((float4*)p)[i] = make_float4(0.f, 0.f, 0.f, 0.f);
}

// ---------------------------------------------------------------------------
// MFMA attention. Block = (h, frame-group, n); 4 waves; wave w owns queries
// [w*16, w*16+16). Cross-frame K prefetch (regs) -> LDS; QK^T scores in regs
// (col=q); register softmax; Pt (stride 232) + swizzled Vt (stride 256) ->
// PV; atomicAdd into mix.
// ---------------------------------------------------------------------------
__global__ __launch_bounds__(256, 2) void attn_mfma(const float* __restrict__ qs_g,
                                                    const float* __restrict__ k_g,
                                                    const float* __restrict__ v_g,
                                                    const int* __restrict__ m_g,
                                                    float* __restrict__ mix_g) {
    const int h = blockIdx.x, fg = blockIdx.y, n = blockIdx.z;

    __shared__ unsigned short KV_s[64 * VST];   // K view: [208][64] swz; Vt view: [64][256] swz
    __shared__ unsigned short Pt_s[64 * PST];   // P^T: [q=64][p<=224]
    __shared__ float bias_s[224];
    __shared__ float linv_s[4][16];

    const int t = threadIdx.x;
    const int w = t >> 6, lane = t & 63, lr = lane & 15, lg = lane >> 4;

    // zero Pt pad cols [208,224) once (covered by first in-loop barrier)
    {
        int qr = t >> 2, c0 = 208 + (t & 3) * 4;
        *(s16x4*)&Pt_s[qr * PST + c0] = (s16x4){0, 0, 0, 0};
    }
    // Q fragments straight to registers (scaled by d^-0.5)
    bf16x8 qb0, qb1;
    {
        const float* qp = qs_g + ((size_t)n * QN + w * 16 + lr) * EE + h * DH + lg * 8;
        f32x4 a = *(const f32x4*)qp, b = *(const f32x4*)(qp + 4);
        f32x4 c = *(const f32x4*)(qp + 32), d = *(const f32x4*)(qp + 36);
#pragma unroll
        for (int i = 0; i < 4; ++i) { a[i] *= 0.125f; b[i] *= 0.125f; c[i] *= 0.125f; d[i] *= 0.125f; }
        qb0 = cvt8(a, b);
        qb1 = cvt8(c, d);
    }

    // ---- prologue: prefetch frame 0's K (bf16 regs) + mask ----
    bf16x8 kpre[7];
    int mpre;
    {
        const size_t kb0 = (size_t)n * KLEN + (size_t)(fg * FPB) * LP;
#pragma unroll
        for (int u = 0; u < 7; ++u) {
            int unit = t + 256 * u;
            int p = unit >> 3, blk = unit & 7;
            f32x4 a = {0.f, 0.f, 0.f, 0.f}, b = {0.f, 0.f, 0.f, 0.f};
            if (unit < KROWS * 8 && p < LP) {
                const float* src = k_g + ((kb0 + p) * HN + h) * DH + blk * 8;
                a = *(const f32x4*)src;
                b = *(const f32x4*)(src + 4);
            }
            kpre[u] = cvt8(a, b);
        }
        mpre = (t < LP) ? m_g[kb0 + t] : 0;
    }

    float mix[4][4];
#pragma unroll
    for (int dt = 0; dt < 4; ++dt)
#pragma unroll
        for (int r = 0; r < 4; ++r) mix[dt][r] = 0.f;

    for (int ff = 0; ff < FPB; ++ff) {
        const size_t kbase = (size_t)n * KLEN + (size_t)(fg * FPB + ff) * LP;

        __syncthreads();  // prev PV / bias readers done before overwrite

        // ---- write prefetched K -> LDS [208][64], XOR-swizzled 16B blocks ----
#pragma unroll
        for (int u = 0; u < 7; ++u) {
            int unit = t + 256 * u;
            if (unit < KROWS * 8) {
                int p = unit >> 3, blk = unit & 7;
                *(bf16x8*)&KV_s[p * 64 + ((blk ^ (p & 7)) << 3)] = kpre[u];
            }
        }
        if (t < 224) bias_s[t] = (t < LP && mpre != 0) ? 0.f : -1e30f;
        __syncthreads();

        // ---- QK^T: lane holds scores for q = w*16+lr, p = tl*16 + lg*4 + r ----
        f32x4 sc[13];
#pragma unroll
        for (int tl = 0; tl < 13; ++tl) {
            int row = tl * 16 + lr;
            bf16x8 a0 = *(const bf16x8*)&KV_s[row * 64 + ((lg ^ (lr & 7)) << 3)];
            bf16x8 a1 = *(const bf16x8*)&KV_s[row * 64 + (((4 + lg) ^ (lr & 7)) << 3)];
            f32x4 z = {0.f, 0.f, 0.f, 0.f};
            z = __builtin_amdgcn_mfma_f32_16x16x32_bf16(a0, qb0, z, 0, 0, 0);
            sc[tl] = __builtin_amdgcn_mfma_f32_16x16x32_bf16(a1, qb1, z, 0, 0, 0);
        }

        // ---- issue V loads (this frame), coalesced: 16 lanes x 16B contiguous ----
        f32x4 va[7], vb[7];
#pragma unroll
        for (int u = 0; u < 7; ++u) {
            int unit = t + 256 * u;
            int pp = unit >> 4, d4 = unit & 15;
            int p0 = pp * 2;
            va[u] = (f32x4){0.f, 0.f, 0.f, 0.f};
            vb[u] = (f32x4){0.f, 0.f, 0.f, 0.f};
            if (p0 < LP) {
                const float* vg = v_g + ((kbase + p0) * HN + h) * DH + d4 * 4;
                va[u] = *(const f32x4*)vg;
                if (p0 + 1 < LP) vb[u] = *(const f32x4*)(vg + (size_t)HN * DH);
            }
        }

        // ---- issue next frame's K loads (f32) + mask; convert after PV ----
        f32x4 ka[7], kb[7];
        if (ff + 1 < FPB) {
            const size_t kbn = kbase + LP;
#pragma unroll
            for (int u = 0; u < 7; ++u) {
                int unit = t + 256 * u;
                int p = unit >> 3, blk = unit & 7;
                ka[u] = (f32x4){0.f, 0.f, 0.f, 0.f};
                kb[u] = (f32x4){0.f, 0.f, 0.f, 0.f};
                if (unit < KROWS * 8 && p < LP) {
                    const float* src = k_g + ((kbn + p) * HN + h) * DH + blk * 8;
                    ka[u] = *(const f32x4*)src;
                    kb[u] = *(const f32x4*)(src + 4);
                }
            }
            mpre = (t < LP) ? m_g[kbn + t] : 0;
        }

        // ---- register softmax over 208 patches ----
        float mx = -FLT_MAX;
#pragma unroll
        for (int tl = 0; tl < 13; ++tl)
#pragma unroll
            for (int r = 0; r < 4; ++r) {
                float sv = sc[tl][r] + bias_s[tl * 16 + lg * 4 + r];
                sc[tl][r] = sv;
                mx = fmaxf(mx, sv);
            }
        mx = fmaxf(mx, __shfl_xor(mx, 16));
        mx = fmaxf(mx, __shfl_xor(mx, 32));
        float sum = 0.f;
#pragma unroll
        for (int tl = 0; tl < 13; ++tl)
#pragma unroll
            for (int r = 0; r < 4; ++r) {
                float e = __expf(sc[tl][r] - mx);
                sc[tl][r] = e;
                sum += e;
            }
        sum += __shfl_xor(sum, 16);
        sum += __shfl_xor(sum, 32);
        if (lane < 16) linv_s[w][lane] = 1.0f / sum;

        // ---- write P^T (wave-private rows, conflict-free) ----
#pragma unroll
        for (int tl = 0; tl < 13; ++tl) {
            s16x4 pb = {(short)bfb(sc[tl][0]), (short)bfb(sc[tl][1]),
                        (short)bfb(sc[tl][2]), (short)bfb(sc[tl][3])};
            *(s16x4*)&Pt_s[(w * 16 + lr) * PST + tl * 16 + lg * 4] = pb;
        }
        __syncthreads();  // all waves done reading K before Vt overwrites union

        // ---- write V^T (pair-packed b32), XOR-swizzled: g(row)=(row+(row>>2))&7 ----
#pragma unroll
        for (int u = 0; u < 7; ++u) {
            int unit = t + 256 * u;
            int pp = unit >> 4, d4 = unit & 15;
            int p0 = pp * 2;
            int blk = p0 >> 3, sub = p0 & 7;
#pragma unroll
            for (int i = 0; i < 4; ++i) {
                int row = d4 * 4 + i;
                int g = (row + (row >> 2)) & 7;
                unsigned pk = (unsigned)bfb(va[u][i]) | ((unsigned)bfb(vb[u][i]) << 16);
                *(unsigned*)&KV_s[row * VST + (((blk ^ g) << 3) | sub)] = pk;
            }
        }
        __syncthreads();

        // ---- PV: C2[q][d] = sum_p Pt[q][p] * Vt[d][p] ----
        f32x4 pv[4];
#pragma unroll
        for (int dt = 0; dt < 4; ++dt) pv[dt] = (f32x4){0.f, 0.f, 0.f, 0.f};
#pragma unroll
        for (int ks = 0; ks < 7; ++ks) {
            bf16x8 a = *(const bf16x8*)&Pt_s[(w * 16 + lr) * PST + ks * 32 + lg * 8];
#pragma unroll
            for (int dt = 0; dt < 4; ++dt) {
                int row = dt * 16 + lr;
                int g = (row + (row >> 2)) & 7;
                bf16x8 b = *(const bf16x8*)&KV_s[row * VST + (((ks * 4 + lg) ^ g) << 3)];
                pv[dt] = __builtin_amdgcn_mfma_f32_16x16x32_bf16(a, b, pv[dt], 0, 0, 0);
            }
        }
        float li[4];
#pragma unroll
        for (int r = 0; r < 4; ++r) li[r] = linv_s[w][lg * 4 + r];
#pragma unroll
        for (int dt = 0; dt < 4; ++dt)
#pragma unroll
            for (int r = 0; r < 4; ++r) mix[dt][r] += pv[dt][r] * li[r];

        // ---- convert prefetched K f32 -> bf16 for next frame ----
        if (ff + 1 < FPB) {
#pragma unroll
            for (int u = 0; u < 7; ++u) kpre[u] = cvt8(ka[u], kb[u]);
        }
    }

    // ---- accumulate into mix[n][q = w*16 + lg*4 + r][h*64 + dt*16 + lr] ----
#pragma unroll
    for (int dt = 0; dt < 4; ++dt)
#pragma unroll
        for (int r = 0; r < 4; ++r)
            atomicAdd(mix_g + ((size_t)n * QN + w * 16 + lg * 4 + r) * EE + h * DH + dt * 16 + lr,
                      mix[dt][r]);
}

// ---------------------------------------------------------------------------
extern "C" void kernel_launch(void* const* d_in, const int* in_sizes, int n_in,
                              void* d_out, int out_size, void* d_ws, size_t ws_size,
                              hipStream_t stream) {
    const float* q  = (const float*)d_in[0];
    const float* k  = (const float*)d_in[1];
    const float* v  = (const float*)d_in[2];
    const int*   m  = (const int*)d_in[3];
    const float* Wi = (const float*)d_in[4];
    const float* Wo = (const float*)d_in[5];

    float* out = (float*)d_out;
    float* qs  = out + (size_t)N_B * QN * EE;  // second output (qs_out), also attn input
    float* mix = (float*)d_ws;                 // 2048x768 fp32 scratch (atomic-accumulated)

    const int mix_n4 = (N_B * QN * EE) / 4;
    dim3 ggrid((N_B * QN) / 64, EE / 48);
    gemm_mfma<<<ggrid, 256, 0, stream>>>(q, Wi, qs);                             // in-proj
    zero_f32<<<(mix_n4 + 255) / 256, 256, 0, stream>>>(mix, mix_n4);             // zero mix
    attn_mfma<<<dim3(HN, FN / FPB, N_B), 256, 0, stream>>>(qs, k, v, m, mix);    // attention
    gemm_mfma<<<ggrid, 256, 0, stream>>>(mix, Wo, out);                          // out-proj
}

// Round 6
// 221.586 us; speedup vs baseline: 1.8529x; 1.8529x over previous
//
#include <hip/hip_runtime.h>
#include <hip/hip_bf16.h>
#include <cfloat>

// dims
#define N_B 32
#define QN 64
#define FN 16
#define LP 196
#define HN 12
#define DH 64
#define EE 768
#define KLEN 3136
#define FPB 4          // frames per block (attn)
#define KROWS 208      // padded patches per frame for QK (13*16)
#define VST 256        // Vt_s row stride in bf16 (512B, pow2 for XOR swizzle)
#define PST 232        // Pt_s row stride in bf16 (464B = 29*16B, conflict-audited free)

typedef short s16x4 __attribute__((ext_vector_type(4)));
typedef __bf16 bf16x8 __attribute__((ext_vector_type(8)));
typedef float f32x4 __attribute__((ext_vector_type(4)));

__device__ __forceinline__ bf16x8 cvt8(f32x4 a, f32x4 b) {
    bf16x8 r;
    r[0] = (__bf16)a[0]; r[1] = (__bf16)a[1]; r[2] = (__bf16)a[2]; r[3] = (__bf16)a[3];
    r[4] = (__bf16)b[0]; r[5] = (__bf16)b[1]; r[6] = (__bf16)b[2]; r[7] = (__bf16)b[3];
    return r;
}
__device__ __forceinline__ unsigned short bfb(float x) {
    return __builtin_bit_cast(unsigned short, (__bf16)x);
}

// ---------------------------------------------------------------------------
// bf16 MFMA GEMM: C[m][n] = sum_k A[m][k] * W[n][k]  (fp32 in, fp32 out)
// BM=64, BN=48, BK=32; 256 threads = 4 waves; wave w owns rows w*16..+16.
// ---------------------------------------------------------------------------
__global__ __launch_bounds__(256) void gemm_mfma(const float* __restrict__ A,
                                                 const float* __restrict__ W,
                                                 float* __restrict__ C) {
    __shared__ unsigned short As[64 * 72];
    __shared__ unsigned short Ws[48 * 72];
    const int t = threadIdx.x;
    const int w = t >> 6, lane = t & 63, lr = lane & 15, lg = lane >> 4;
    const int m0 = blockIdx.x * 64;
    const int n0 = blockIdx.y * 48;

    f32x4 acc[3];
#pragma unroll
    for (int ct = 0; ct < 3; ++ct) acc[ct] = (f32x4){0.f, 0.f, 0.f, 0.f};

    for (int k0 = 0; k0 < EE; k0 += 32) {
        {
            int row = t >> 2, cb = t & 3;
            const float* src = A + (size_t)(m0 + row) * EE + k0 + cb * 8;
            f32x4 a = *(const f32x4*)src, b = *(const f32x4*)(src + 4);
            *(bf16x8*)&As[row * 72 + cb * 8] = cvt8(a, b);
        }
        if (t < 192) {
            int row = t >> 2, cb = t & 3;
            const float* src = W + (size_t)(n0 + row) * EE + k0 + cb * 8;
            f32x4 a = *(const f32x4*)src, b = *(const f32x4*)(src + 4);
            *(bf16x8*)&Ws[row * 72 + cb * 8] = cvt8(a, b);
        }
        __syncthreads();
        bf16x8 a = *(const bf16x8*)&As[(w * 16 + lr) * 72 + lg * 8];
#pragma unroll
        for (int ct = 0; ct < 3; ++ct) {
            bf16x8 b = *(const bf16x8*)&Ws[(ct * 16 + lr) * 72 + lg * 8];
            acc[ct] = __builtin_amdgcn_mfma_f32_16x16x32_bf16(a, b, acc[ct], 0, 0, 0);
        }
        __syncthreads();
    }
#pragma unroll
    for (int ct = 0; ct < 3; ++ct)
#pragma unroll
        for (int r = 0; r < 4; ++r)
            C[(size_t)(m0 + w * 16 + lg * 4 + r) * EE + n0 + ct * 16 + lr] = acc[ct][r];
}

__global__ __launch_bounds__(256) void zero_f32(float* __restrict__ p, int n4) {
    int i = blockIdx.x * 256 + threadIdx.x;
    if (i < n4) ((float4*)p)[i] = make_float4(0.f, 0.f, 0.f, 0.f);
}

// ---------------------------------------------------------------------------
// MFMA attention. Block = (h, frame-group, n); 4 waves; wave w owns queries
// [w*16, w*16+16). Per frame: K staged to swizzled [208][64] LDS; QK^T scores
// in regs (col=q); register softmax; Pt (stride 232) + pow2-XOR-swizzled Vt
// (stride 256, coalesced global V loads) -> PV; atomicAdd into mix.
// ---------------------------------------------------------------------------
__global__ __launch_bounds__(256, 2) void attn_mfma(const float* __restrict__ qs_g,
                                                    const float* __restrict__ k_g,
                                                    const float* __restrict__ v_g,
                                                    const int* __restrict__ m_g,
                                                    float* __restrict__ mix_g) {
    const int h = blockIdx.x, fg = blockIdx.y, n = blockIdx.z;

    __shared__ unsigned short KV_s[64 * VST];   // K view: [208][64] swz; Vt view: [64][256] swz
    __shared__ unsigned short Pt_s[64 * PST];   // P^T: [q=64][p<=224]
    __shared__ float bias_s[224];
    __shared__ float linv_s[4][16];

    const int t = threadIdx.x;
    const int w = t >> 6, lane = t & 63, lr = lane & 15, lg = lane >> 4;

    // zero Pt pad cols [208,224) once (covered by first in-loop barrier)
    {
        int qr = t >> 2, c0 = 208 + (t & 3) * 4;
        *(s16x4*)&Pt_s[qr * PST + c0] = (s16x4){0, 0, 0, 0};
    }
    // Q fragments straight to registers (scaled by d^-0.5)
    bf16x8 qb0, qb1;
    {
        const float* qp = qs_g + ((size_t)n * QN + w * 16 + lr) * EE + h * DH + lg * 8;
        f32x4 a = *(const f32x4*)qp, b = *(const f32x4*)(qp + 4);
        f32x4 c = *(const f32x4*)(qp + 32), d = *(const f32x4*)(qp + 36);
#pragma unroll
        for (int i = 0; i < 4; ++i) { a[i] *= 0.125f; b[i] *= 0.125f; c[i] *= 0.125f; d[i] *= 0.125f; }
        qb0 = cvt8(a, b);
        qb1 = cvt8(c, d);
    }

    float mix[4][4];
#pragma unroll
    for (int dt = 0; dt < 4; ++dt)
#pragma unroll
        for (int r = 0; r < 4; ++r) mix[dt][r] = 0.f;

    for (int ff = 0; ff < FPB; ++ff) {
        const size_t kbase = (size_t)n * KLEN + (size_t)(fg * FPB + ff) * LP;

        __syncthreads();  // prev PV / bias readers done before overwrite

        // ---- stage K [208][64] bf16, XOR-swizzled 16B blocks ----
#pragma unroll
        for (int u = 0; u < 7; ++u) {
            int unit = t + 256 * u;
            if (unit < KROWS * 8) {
                int p = unit >> 3, blk = unit & 7;
                f32x4 a = {0.f, 0.f, 0.f, 0.f}, b = {0.f, 0.f, 0.f, 0.f};
                if (p < LP) {
                    const float* src = k_g + ((kbase + p) * HN + h) * DH + blk * 8;
                    a = *(const f32x4*)src;
                    b = *(const f32x4*)(src + 4);
                }
                *(bf16x8*)&KV_s[p * 64 + ((blk ^ (p & 7)) << 3)] = cvt8(a, b);
            }
        }
        if (t < 224) {
            float bv = -1e30f;
            if (t < LP && m_g[kbase + t] != 0) bv = 0.f;
            bias_s[t] = bv;
        }
        __syncthreads();

        // ---- QK^T: lane holds scores for q = w*16+lr, p = tl*16 + lg*4 + r ----
        f32x4 sc[13];
#pragma unroll
        for (int tl = 0; tl < 13; ++tl) {
            int row = tl * 16 + lr;
            bf16x8 a0 = *(const bf16x8*)&KV_s[row * 64 + ((lg ^ (lr & 7)) << 3)];
            bf16x8 a1 = *(const bf16x8*)&KV_s[row * 64 + (((4 + lg) ^ (lr & 7)) << 3)];
            f32x4 z = {0.f, 0.f, 0.f, 0.f};
            z = __builtin_amdgcn_mfma_f32_16x16x32_bf16(a0, qb0, z, 0, 0, 0);
            sc[tl] = __builtin_amdgcn_mfma_f32_16x16x32_bf16(a1, qb1, z, 0, 0, 0);
        }

        // ---- issue V loads (coalesced: 16 lanes x 16B contiguous) ----
        f32x4 va[7], vb[7];
#pragma unroll
        for (int u = 0; u < 7; ++u) {
            int unit = t + 256 * u;
            int pp = unit >> 4, d4 = unit & 15;
            int p0 = pp * 2;
            va[u] = (f32x4){0.f, 0.f, 0.f, 0.f};
            vb[u] = (f32x4){0.f, 0.f, 0.f, 0.f};
            if (p0 < LP) {
                const float* vg = v_g + ((kbase + p0) * HN + h) * DH + d4 * 4;
                va[u] = *(const f32x4*)vg;
                if (p0 + 1 < LP) vb[u] = *(const f32x4*)(vg + (size_t)HN * DH);
            }
        }

        // ---- register softmax over 208 patches ----
        float mx = -FLT_MAX;
#pragma unroll
        for (int tl = 0; tl < 13; ++tl)
#pragma unroll
            for (int r = 0; r < 4; ++r) {
                float sv = sc[tl][r] + bias_s[tl * 16 + lg * 4 + r];
                sc[tl][r] = sv;
                mx = fmaxf(mx, sv);
            }
        mx = fmaxf(mx, __shfl_xor(mx, 16));
        mx = fmaxf(mx, __shfl_xor(mx, 32));
        float sum = 0.f;
#pragma unroll
        for (int tl = 0; tl < 13; ++tl)
#pragma unroll
            for (int r = 0; r < 4; ++r) {
                float e = __expf(sc[tl][r] - mx);
                sc[tl][r] = e;
                sum += e;
            }
        sum += __shfl_xor(sum, 16);
        sum += __shfl_xor(sum, 32);
        if (lane < 16) linv_s[w][lane] = 1.0f / sum;

        // ---- write P^T (wave-private rows, conflict-free) ----
#pragma unroll
        for (int tl = 0; tl < 13; ++tl) {
            s16x4 pb = {(short)bfb(sc[tl][0]), (short)bfb(sc[tl][1]),
                        (short)bfb(sc[tl][2]), (short)bfb(sc[tl][3])};
            *(s16x4*)&Pt_s[(w * 16 + lr) * PST + tl * 16 + lg * 4] = pb;
        }
        __syncthreads();  // all waves done reading K before Vt overwrites union

        // ---- write V^T (pair-packed b32), XOR-swizzled: g(row)=(row+(row>>2))&7 ----
#pragma unroll
        for (int u = 0; u < 7; ++u) {
            int unit = t + 256 * u;
            int pp = unit >> 4, d4 = unit & 15;
            int p0 = pp * 2;
            int blk = p0 >> 3, sub = p0 & 7;
#pragma unroll
            for (int i = 0; i < 4; ++i) {
                int row = d4 * 4 + i;
                int g = (row + (row >> 2)) & 7;
                unsigned pk = (unsigned)bfb(va[u][i]) | ((unsigned)bfb(vb[u][i]) << 16);
                *(unsigned*)&KV_s[row * VST + (((blk ^ g) << 3) | sub)] = pk;
            }
        }
        __syncthreads();

        // ---- PV: C2[q][d] = sum_p Pt[q][p] * Vt[d][p] ----
        f32x4 pv[4];
#pragma unroll
        for (int dt = 0; dt < 4; ++dt) pv[dt] = (f32x4){0.f, 0.f, 0.f, 0.f};
#pragma unroll
        for (int ks = 0; ks < 7; ++ks) {
            bf16x8 a = *(const bf16x8*)&Pt_s[(w * 16 + lr) * PST + ks * 32 + lg * 8];
#pragma unroll
            for (int dt = 0; dt < 4; ++dt) {
                int row = dt * 16 + lr;
                int g = (row + (row >> 2)) & 7;
                bf16x8 b = *(const bf16x8*)&KV_s[row * VST + (((ks * 4 + lg) ^ g) << 3)];
                pv[dt] = __builtin_amdgcn_mfma_f32_16x16x32_bf16(a, b, pv[dt], 0, 0, 0);
            }
        }
        float li[4];
#pragma unroll
        for (int r = 0; r < 4; ++r) li[r] = linv_s[w][lg * 4 + r];
#pragma unroll
        for (int dt = 0; dt < 4; ++dt)
#pragma unroll
            for (int r = 0; r < 4; ++r) mix[dt][r] += pv[dt][r] * li[r];
    }

    // ---- accumulate into mix[n][q = w*16 + lg*4 + r][h*64 + dt*16 + lr] ----
#pragma unroll
    for (int dt = 0; dt < 4; ++dt)
#pragma unroll
        for (int r = 0; r < 4; ++r)
            atomicAdd(mix_g + ((size_t)n * QN + w * 16 + lg * 4 + r) * EE + h * DH + dt * 16 + lr,
                      mix[dt][r]);
}

// ---------------------------------------------------------------------------
extern "C" void kernel_launch(void* const* d_in, const int* in_sizes, int n_in,
                              void* d_out, int out_size, void* d_ws, size_t ws_size,
                              hipStream_t stream) {
    const float* q  = (const float*)d_in[0];
    const float* k  = (const float*)d_in[1];
    const float* v  = (const float*)d_in[2];
    const int*   m  = (const int*)d_in[3];
    const float* Wi = (const float*)d_in[4];
    const float* Wo = (const float*)d_in[5];

    float* out = (float*)d_out;
    float* qs  = out + (size_t)N_B * QN * EE;  // second output (qs_out), also attn input
    float* mix = (float*)d_ws;                 // 2048x768 fp32 scratch (atomic-accumulated)

    const int mix_n4 = (N_B * QN * EE) / 4;
    dim3 ggrid((N_B * QN) / 64, EE / 48);
    gemm_mfma<<<ggrid, 256, 0, stream>>>(q, Wi, qs);                             // in-proj
    zero_f32<<<(mix_n4 + 255) / 256, 256, 0, stream>>>(mix, mix_n4);             // zero mix
    attn_mfma<<<dim3(HN, FN / FPB, N_B), 256, 0, stream>>>(qs, k, v, m, mix);    // attention
    gemm_mfma<<<ggrid, 256, 0, stream>>>(mix, Wo, out);                          // out-proj
}